// Round 3
// baseline (328.314 us; speedup 1.0000x reference)
//
#include <hip/hip_runtime.h>
#include <hip/hip_bf16.h>

typedef unsigned short u16;
typedef __attribute__((ext_vector_type(8))) short short8;
typedef __attribute__((ext_vector_type(16))) float f32x16;

#define MFMA(A,B,C) __builtin_amdgcn_mfma_f32_32x32x16_bf16(A,B,C,0,0,0)
#define NEG_INF -1e30f

__device__ __forceinline__ unsigned cvtpk_bf16(float a, float b) {
    unsigned r;
    asm("v_cvt_pk_bf16_f32 %0, %1, %2" : "=v"(r) : "v"(a), "v"(b));
    return r;
}
__device__ __forceinline__ void permswap(unsigned &a, unsigned &b) {
    auto r = __builtin_amdgcn_permlane32_swap(a, b, false, false);
    a = r[0]; b = r[1];
}
union W4u { unsigned u[4]; short8 v; };
__device__ __forceinline__ short8 mk8(unsigned a, unsigned b, unsigned c, unsigned d) {
    W4u w; w.u[0] = a; w.u[1] = b; w.u[2] = c; w.u[3] = d; return w.v;
}
__device__ __forceinline__ void split_words(float p0, float p1, unsigned &wh, unsigned &wl) {
    wh = cvtpk_bf16(p0, p1);
    float h0 = __uint_as_float(wh << 16);
    float h1 = __uint_as_float(wh & 0xffff0000u);
    wl = cvtpk_bf16(p0 - h0, p1 - h1);
}
__device__ __forceinline__ void split_store(float v, u16* ph, u16* pl) {
    __hip_bfloat16 h = __float2bfloat16(v);
    float hf = __bfloat162float(h);
    __hip_bfloat16 l = __float2bfloat16(v - hf);
    *ph = *(u16*)&h;
    *pl = *(u16*)&l;
}
__device__ __forceinline__ short8 ld8(const u16* p) { return *(const short8*)p; }

// chunks (CH KV-tiles each) in strips [0, qw) of one batch; closed form.
__device__ __forceinline__ int chunks_before(int qw, int CH) {
    int a = qw >> 1, p = qw & 1;
    int u = a / CH, r = a - u * CH;
    int S = CH * (u * (u + 1) / 2) + r * (u + 1);  // sum_{i=1..a} ceil(i/CH)
    int g = (a + CH) / CH;                          // ceil((a+1)/CH)
    return 2 * S + p * g;
}

// ---------------------------------------------------------------------------
// Convert all 6 W (fp32 [512][64]) -> transposed hi/lo bf16 [64][512].
// LDS transpose so both global read and write are coalesced.
// ---------------------------------------------------------------------------
__global__ void convw_kernel(
    const float* __restrict__ Wq, const float* __restrict__ Wk, const float* __restrict__ Wv,
    const float* __restrict__ Wqs, const float* __restrict__ Wks, const float* __restrict__ Wvs,
    u16* __restrict__ wbase)
{
    const int z = blockIdx.y;          // 0..5
    const int tile = blockIdx.x;       // 0..7 (d-chunks of 64)
    const float* W = (z == 0) ? Wq : (z == 1) ? Wk : (z == 2) ? Wv
                   : (z == 3) ? Wqs : (z == 4) ? Wks : Wvs;
    u16* oh = wbase + (size_t)z * 2 * 32768;
    u16* ol = oh + 32768;
    __shared__ float Xs[64][65];
    const int tid = threadIdx.x;
    const int d0 = tile * 64;
    #pragma unroll
    for (int k = 0; k < 16; ++k) {
        int idx = tid + k * 256;
        int d = idx >> 6, c = idx & 63;
        Xs[d][c] = W[(size_t)(d0 + d) * 64 + c];
    }
    __syncthreads();
    #pragma unroll
    for (int k = 0; k < 16; ++k) {
        int idx = tid + k * 256;
        int c = idx >> 6, dd = idx & 63;
        split_store(Xs[dd][c], oh + (size_t)c * 512 + d0 + dd,
                               ol + (size_t)c * 512 + d0 + dd);
    }
}

// ---------------------------------------------------------------------------
// QKV projection via split-bf16 MFMA. 1 wave/block, 32 rows/strip.
// Blocks 0..511: mid weights, edge-row stores predicated off.
// Blocks 512..513: the 64 edge rows (2 batches each) with _s weights.
// ---------------------------------------------------------------------------
__global__ __launch_bounds__(64, 2) void proj_kernel(
    const float* __restrict__ x, const u16* __restrict__ wbase,
    u16* __restrict__ qh, u16* __restrict__ ql,
    u16* __restrict__ kh, u16* __restrict__ kl,
    u16* __restrict__ vth, u16* __restrict__ vtl)
{
    const int sidx = blockIdx.x;
    const bool edge = (sidx >= 512);
    const int lane = threadIdx.x;
    const int l31 = lane & 31, hi = lane >> 5;

    // weight set: mid (z=0..2) or _s (z=3..5)
    const u16* wb = wbase + (edge ? (size_t)3 * 2 * 32768 : 0);
    const u16* wqh_ = wb;                const u16* wql_ = wb + 32768;
    const u16* wkh_ = wb + 2 * 32768;    const u16* wkl_ = wb + 3 * 32768;
    const u16* wvh_ = wb + 4 * 32768;    const u16* wvl_ = wb + 5 * 32768;

    // global x-row for this lane (A-operand row / v-store column)
    int growA;
    if (!edge) growA = sidx * 32 + l31;
    else {
        int e = sidx - 512, rb = l31 >> 4, i = l31 & 15;
        growA = (2 * e + rb) * 4096 + (i < 8 ? i : 4080 + i);
    }
    const float* xrow = x + (size_t)growA * 512;

    f32x16 aq[2] = {{}, {}}, ak[2] = {{}, {}}, av[2] = {{}, {}};
    #pragma unroll 2
    for (int s = 0; s < 32; ++s) {
        const int d0 = s * 16 + 8 * hi;
        float4 xa = *(const float4*)(xrow + d0);
        float4 xb = *(const float4*)(xrow + d0 + 4);
        unsigned xh_[4], xl_[4];
        split_words(xa.x, xa.y, xh_[0], xl_[0]);
        split_words(xa.z, xa.w, xh_[1], xl_[1]);
        split_words(xb.x, xb.y, xh_[2], xl_[2]);
        split_words(xb.z, xb.w, xh_[3], xl_[3]);
        short8 xhf = mk8(xh_[0], xh_[1], xh_[2], xh_[3]);
        short8 xlf = mk8(xl_[0], xl_[1], xl_[2], xl_[3]);
        #pragma unroll
        for (int half = 0; half < 2; ++half) {
            size_t wof = (size_t)(half * 32 + l31) * 512 + d0;
            short8 qH = ld8(wqh_ + wof), qL = ld8(wql_ + wof);
            short8 kH = ld8(wkh_ + wof), kL = ld8(wkl_ + wof);
            short8 vH = ld8(wvh_ + wof), vL = ld8(wvl_ + wof);
            aq[half] = MFMA(xhf, qH, aq[half]);
            aq[half] = MFMA(xhf, qL, aq[half]);
            aq[half] = MFMA(xlf, qH, aq[half]);
            ak[half] = MFMA(xhf, kH, ak[half]);
            ak[half] = MFMA(xhf, kL, ak[half]);
            ak[half] = MFMA(xlf, kH, ak[half]);
            av[half] = MFMA(vH, xhf, av[half]);
            av[half] = MFMA(vL, xhf, av[half]);
            av[half] = MFMA(vH, xlf, av[half]);
        }
    }
    // v-store lane predicate (column = growA)
    const int bv = growA >> 12, tv = growA & 4095;
    const bool vstore = edge || (tv >= 8 && tv < 4088);
    #pragma unroll
    for (int half = 0; half < 2; ++half) {
        #pragma unroll
        for (int r = 0; r < 16; ++r) {
            const int crow = (r & 3) + 8 * (r >> 2) + 4 * hi;
            const int col = half * 32 + l31;
            int growC; bool qkstore;
            if (!edge) {
                int t = sidx * 32 + crow, tin = t & 4095;
                qkstore = (tin >= 8 && tin < 4088); growC = t;
            } else {
                int e = sidx - 512, rb = crow >> 4, i = crow & 15;
                growC = (2 * e + rb) * 4096 + (i < 8 ? i : 4080 + i);
                qkstore = true;
            }
            if (qkstore) {
                size_t qo = (size_t)growC * 64 + col;
                split_store(aq[half][r] * 0.125f, qh + qo, ql + qo);
                split_store(ak[half][r], kh + qo, kl + qo);
            }
            if (vstore) {
                size_t vo = ((size_t)bv * 64 + half * 32 + crow) * 4096 + tv;
                split_store(av[half][r], vth + vo, vtl + vo);
            }
        }
    }
}

// ---------------------------------------------------------------------------
// Flash attention: uniform chunks of CH KV-tiles. 1 wave/block.
// bid -> (batch via XCD affinity, chunk); chunk -> (qw, tile range) via
// closed-form cumulative + binary search. Swapped QK^T, lane-local softmax.
// ---------------------------------------------------------------------------
__global__ __launch_bounds__(64, 4) void flash_kernel(
    const u16* __restrict__ qhB, const u16* __restrict__ qlB,
    const u16* __restrict__ khB, const u16* __restrict__ klB,
    const u16* __restrict__ vthB, const u16* __restrict__ vtlB,
    float* __restrict__ Opart, float* __restrict__ mpart, float* __restrict__ lpart,
    int CH, int G)
{
    const int bid = blockIdx.x;
    const int b = (bid >> 1) & 3;                       // batch -> XCD pair
    const int chunk = ((bid >> 3) << 1) | (bid & 1);    // 0..G-1
    // invert chunk -> qw
    int qw = 0;
    for (int step = 64; step; step >>= 1) {
        int cand = qw + step;
        if (cand < 128 && chunks_before(cand, CH) <= chunk) qw = cand;
    }
    const int cloc = chunk - chunks_before(qw, CH);
    const int nt = (qw >> 1) + 1;
    const int klo = cloc * CH;
    const int khi = min(nt, klo + CH);
    const int lane = threadIdx.x, l31 = lane & 31, hi = lane >> 5;
    const int q0 = qw * 32;

    const size_t qoff = ((size_t)b * 4096 + q0 + l31) * 64 + 8 * hi;
    short8 qhf[4], qlf[4];
    #pragma unroll
    for (int s = 0; s < 4; ++s) {
        qhf[s] = ld8(qhB + qoff + 16 * s);
        qlf[s] = ld8(qlB + qoff + 16 * s);
    }
    const u16* kh_ = khB + (size_t)b * 4096 * 64;
    const u16* kl_ = klB + (size_t)b * 4096 * 64;
    const u16* vth_ = vthB + (size_t)b * 64 * 4096;
    const u16* vtl_ = vtlB + (size_t)b * 64 * 4096;

    f32x16 o[2] = {{}, {}};
    float mrun = NEG_INF, lrun = 0.f;

    for (int kb = klo; kb < khi; ++kb) {
        const int kk = kb * 64;
        short8 kfh[2][4], kfl[2][4];
        #pragma unroll
        for (int sub = 0; sub < 2; ++sub)
            #pragma unroll
            for (int s = 0; s < 4; ++s) {
                size_t off = (size_t)(kk + 32 * sub + l31) * 64 + 16 * s + 8 * hi;
                kfh[sub][s] = ld8(kh_ + off);
                kfl[sub][s] = ld8(kl_ + off);
            }
        short8 vfh[2][4], vfl[2][4];
        #pragma unroll
        for (int sub = 0; sub < 2; ++sub)
            #pragma unroll
            for (int s = 0; s < 4; ++s) {
                size_t off = (size_t)(sub * 32 + l31) * 4096 + kk + 16 * s + 8 * hi;
                vfh[sub][s] = ld8(vth_ + off);
                vfl[sub][s] = ld8(vtl_ + off);
            }
        f32x16 c[2] = {{}, {}};
        __builtin_amdgcn_s_setprio(1);
        #pragma unroll
        for (int s = 0; s < 4; ++s) {
            c[0] = MFMA(kfh[0][s], qhf[s], c[0]);
            c[0] = MFMA(kfh[0][s], qlf[s], c[0]);
            c[0] = MFMA(kfl[0][s], qhf[s], c[0]);
            c[1] = MFMA(kfh[1][s], qhf[s], c[1]);
            c[1] = MFMA(kfh[1][s], qlf[s], c[1]);
            c[1] = MFMA(kfl[1][s], qhf[s], c[1]);
        }
        __builtin_amdgcn_s_setprio(0);
        if (kb == nt - 1) {
            const int qloc = l31 + 32 * (qw & 1);
            #pragma unroll
            for (int r = 0; r < 16; ++r) {
                int krow = (r & 3) + 8 * (r >> 2) + 4 * hi;
                if (krow > qloc) c[0][r] = NEG_INF;
                if (krow + 32 > qloc) c[1][r] = NEG_INF;
            }
        }
        float mx = NEG_INF;
        #pragma unroll
        for (int r = 0; r < 16; ++r) mx = fmaxf(mx, fmaxf(c[0][r], c[1][r]));
        mx = fmaxf(mx, __shfl_xor(mx, 32));
        float mnew = fmaxf(mrun, mx);
        float alpha = __expf(mrun - mnew);
        mrun = mnew;
        float sum = 0.f;
        #pragma unroll
        for (int r = 0; r < 16; ++r) { c[0][r] = __expf(c[0][r] - mnew); sum += c[0][r]; }
        #pragma unroll
        for (int r = 0; r < 16; ++r) { c[1][r] = __expf(c[1][r] - mnew); sum += c[1][r]; }
        sum += __shfl_xor(sum, 32);
        lrun = lrun * alpha + sum;
        #pragma unroll
        for (int r = 0; r < 16; ++r) { o[0][r] *= alpha; o[1][r] *= alpha; }
        short8 pbh[4], pbl[4];
        #pragma unroll
        for (int t = 0; t < 2; ++t) {
            #pragma unroll
            for (int g = 0; g < 2; ++g) {
                unsigned wAh, wAl, wBh, wBl, wCh, wCl, wDh, wDl;
                split_words(c[t][8 * g + 0], c[t][8 * g + 1], wAh, wAl);
                split_words(c[t][8 * g + 2], c[t][8 * g + 3], wBh, wBl);
                split_words(c[t][8 * g + 4], c[t][8 * g + 5], wCh, wCl);
                split_words(c[t][8 * g + 6], c[t][8 * g + 7], wDh, wDl);
                permswap(wAh, wCh); permswap(wBh, wDh);
                permswap(wAl, wCl); permswap(wBl, wDl);
                pbh[2 * t + g] = mk8(wAh, wBh, wCh, wDh);
                pbl[2 * t + g] = mk8(wAl, wBl, wCl, wDl);
            }
        }
        __builtin_amdgcn_s_setprio(1);
        #pragma unroll
        for (int s = 0; s < 4; ++s) {
            o[0] = MFMA(vfh[0][s], pbh[s], o[0]);
            o[0] = MFMA(vfh[0][s], pbl[s], o[0]);
            o[0] = MFMA(vfl[0][s], pbh[s], o[0]);
            o[1] = MFMA(vfh[1][s], pbh[s], o[1]);
            o[1] = MFMA(vfh[1][s], pbl[s], o[1]);
            o[1] = MFMA(vfl[1][s], pbh[s], o[1]);
        }
        __builtin_amdgcn_s_setprio(0);
    }
    const int pid = b * G + chunk;
    float* Op = Opart + (size_t)pid * 2048;   // [64 v][32 q], coalesced in q
    #pragma unroll
    for (int r = 0; r < 16; ++r) {
        int v0 = (r & 3) + 8 * (r >> 2) + 4 * hi;
        Op[v0 * 32 + l31] = o[0][r];
        Op[(v0 + 32) * 32 + l31] = o[1][r];
    }
    if (hi == 0) {
        mpart[pid * 32 + l31] = mrun;
        lpart[pid * 32 + l31] = lrun;
    }
}

// ---------------------------------------------------------------------------
// Merge: per (b,qw) combine its g chunks, normalize, write out[t][v].
// Register accumulation (coalesced reads) + LDS transpose (coalesced write).
// ---------------------------------------------------------------------------
__global__ void merge_kernel(
    const float* __restrict__ Opart, const float* __restrict__ mpart,
    const float* __restrict__ lpart, float* __restrict__ out, int CH, int G)
{
    __shared__ float wgt[16][32];
    __shared__ float tr[32][65];
    const int b = blockIdx.x >> 7, qw = blockIdx.x & 127;
    const int nt = (qw >> 1) + 1;
    const int g = (nt + CH - 1) / CH;
    const int base = b * G + chunks_before(qw, CH);
    const int tid = threadIdx.x;
    if (tid < 32) {
        float M = NEG_INF;
        for (int s = 0; s < g; ++s) M = fmaxf(M, mpart[(base + s) * 32 + tid]);
        float L = 0.f;
        for (int s = 0; s < g; ++s)
            L += lpart[(base + s) * 32 + tid] * __expf(mpart[(base + s) * 32 + tid] - M);
        float inv = 1.0f / L;
        for (int s = 0; s < g; ++s)
            wgt[s][tid] = __expf(mpart[(base + s) * 32 + tid] - M) * inv;
    }
    __syncthreads();
    float acc[8] = {};
    for (int s = 0; s < g; ++s) {
        const float* Op = Opart + (size_t)(base + s) * 2048;
        #pragma unroll
        for (int k = 0; k < 8; ++k) {
            int i = tid + k * 256;           // i = v*32 + q
            acc[k] += wgt[s][i & 31] * Op[i];
        }
    }
    #pragma unroll
    for (int k = 0; k < 8; ++k) {
        int i = tid + k * 256;
        tr[i & 31][i >> 5] = acc[k];
    }
    __syncthreads();
    float* dst = out + ((size_t)b * 4096 + qw * 32) * 64;
    #pragma unroll
    for (int k = 0; k < 8; ++k) {
        int j = tid + k * 256;               // j = q*64 + v
        dst[j] = tr[j >> 6][j & 63];
    }
}

extern "C" void kernel_launch(void* const* d_in, const int* in_sizes, int n_in,
                              void* d_out, int out_size, void* d_ws, size_t ws_size,
                              hipStream_t stream) {
    const float* x   = (const float*)d_in[0];
    const float* Wq  = (const float*)d_in[1];
    const float* Wk  = (const float*)d_in[2];
    const float* Wv  = (const float*)d_in[3];
    const float* Wqs = (const float*)d_in[4];
    const float* Wks = (const float*)d_in[5];
    const float* Wvs = (const float*)d_in[6];
    float* out = (float*)d_out;

    char* ws = (char*)d_ws;
    const size_t MB = 1024 * 1024;
    u16* qh  = (u16*)(ws);
    u16* ql  = (u16*)(ws + 2 * MB);
    u16* kh  = (u16*)(ws + 4 * MB);
    u16* kl  = (u16*)(ws + 6 * MB);
    u16* vth = (u16*)(ws + 8 * MB);
    u16* vtl = (u16*)(ws + 10 * MB);
    u16* wbase = (u16*)(ws + 12 * MB);                 // 12 x 64KB
    float* mpart = (float*)(ws + 13 * MB);             // <= 557KB
    float* lpart = (float*)(ws + 13 * MB + 768 * 1024);
    float* Opart = (float*)(ws + 15 * MB);             // 4*G*8KB

    // chunk size / partial-buffer sizing by available workspace
    int CH = 4, G = 1088;                               // Opart 34 MB
    if (ws_size < 15 * MB + (size_t)4 * 1088 * 8192) { CH = 8;  G = 576; }  // 18 MB
    if (ws_size < 15 * MB + (size_t)4 * 576  * 8192) { CH = 16; G = 320; }  // 10 MB

    convw_kernel<<<dim3(8, 6), 256, 0, stream>>>(Wq, Wk, Wv, Wqs, Wks, Wvs, wbase);
    proj_kernel<<<514, 64, 0, stream>>>(x, wbase, qh, ql, kh, kl, vth, vtl);
    flash_kernel<<<4 * G, 64, 0, stream>>>(qh, ql, kh, kl, vth, vtl,
                                           Opart, mpart, lpart, CH, G);
    merge_kernel<<<512, 256, 0, stream>>>(Opart, mpart, lpart, out, CH, G);
}

// Round 5
// 164.080 us; speedup vs baseline: 2.0009x; 2.0009x over previous
//
#include <hip/hip_runtime.h>
#include <hip/hip_bf16.h>

typedef unsigned short u16;
typedef __attribute__((ext_vector_type(8))) short short8;
typedef __attribute__((ext_vector_type(16))) float f32x16;

#define MFMA(A,B,C) __builtin_amdgcn_mfma_f32_32x32x16_bf16(A,B,C,0,0,0)
#define NEG_INF -1e30f

__device__ __forceinline__ unsigned cvtpk_bf16(float a, float b) {
    unsigned r;
    asm("v_cvt_pk_bf16_f32 %0, %1, %2" : "=v"(r) : "v"(a), "v"(b));
    return r;
}
__device__ __forceinline__ void permswap(unsigned &a, unsigned &b) {
    auto r = __builtin_amdgcn_permlane32_swap(a, b, false, false);
    a = r[0]; b = r[1];
}
union W4u { unsigned u[4]; short8 v; };
__device__ __forceinline__ short8 mk8(unsigned a, unsigned b, unsigned c, unsigned d) {
    W4u w; w.u[0] = a; w.u[1] = b; w.u[2] = c; w.u[3] = d; return w.v;
}
__device__ __forceinline__ void split_words(float p0, float p1, unsigned &wh, unsigned &wl) {
    wh = cvtpk_bf16(p0, p1);
    float h0 = __uint_as_float(wh << 16);
    float h1 = __uint_as_float(wh & 0xffff0000u);
    wl = cvtpk_bf16(p0 - h0, p1 - h1);
}
__device__ __forceinline__ void split_store(float v, u16* ph, u16* pl) {
    __hip_bfloat16 h = __float2bfloat16(v);
    float hf = __bfloat162float(h);
    __hip_bfloat16 l = __float2bfloat16(v - hf);
    *ph = *(u16*)&h;
    *pl = *(u16*)&l;
}
__device__ __forceinline__ short8 ld8(const u16* p) { return *(const short8*)p; }

// chunks (CH=1<<lc KV-tiles each) in q-strips [0, qw) of one batch
__device__ __forceinline__ int chunks_before(int qw, int lc) {
    int CH = 1 << lc;
    int a = qw >> 1, p = qw & 1;
    int u = a >> lc, r = a - (u << lc);
    int S = ((u * (u + 1)) >> 1 << lc) + r * (u + 1);
    int g = (a + CH) >> lc;
    return 2 * S + p * g;
}

// fragment-linear index for Q/K: row grow (global), col 0..63
__device__ __forceinline__ size_t qk_idx(int grow, int col) {
    return (size_t)(grow >> 5) * 2048 + (col >> 4) * 512 + (grow & 31) * 16
         + ((col >> 3) & 1) * 8 + (col & 7);
}

// ---------------------------------------------------------------------------
// Weights (fp32 [512][64]) -> fragment-linear hi/lo bf16 planes.
// plane[s*1024 + r*16 + hi*8 + j] = W[s*16+hi*8+j][r]
// ---------------------------------------------------------------------------
__global__ void convw_kernel(
    const float* __restrict__ Wq, const float* __restrict__ Wk, const float* __restrict__ Wv,
    const float* __restrict__ Wqs, const float* __restrict__ Wks, const float* __restrict__ Wvs,
    u16* __restrict__ wbase)
{
    const int z = blockIdx.y;      // 0..5
    const int tile = blockIdx.x;   // 0..7 (64-d chunks)
    const float* W = (z == 0) ? Wq : (z == 1) ? Wk : (z == 2) ? Wv
                   : (z == 3) ? Wqs : (z == 4) ? Wks : Wvs;
    u16* oh = wbase + (size_t)z * 65536;
    u16* ol = oh + 32768;
    __shared__ float Xs[64][65];
    const int tid = threadIdx.x;
    const int d0 = tile * 64;
    #pragma unroll
    for (int k = 0; k < 16; ++k) {
        int idx = tid + k * 256;
        int d = idx >> 6, c = idx & 63;
        Xs[d][c] = W[(size_t)(d0 + d) * 64 + c];
    }
    __syncthreads();
    #pragma unroll
    for (int k = 0; k < 16; ++k) {
        int odx = tid + k * 256;
        int j = odx & 7, hi8 = (odx >> 3) & 1, r = (odx >> 4) & 63, sl = odx >> 10;
        size_t oidx = (size_t)(tile * 4 + sl) * 1024 + r * 16 + hi8 * 8 + j;
        split_store(Xs[sl * 16 + hi8 * 8 + j][r], oh + oidx, ol + oidx);
    }
}

// ---------------------------------------------------------------------------
// QKV projection. 2-wave blocks (K-split d<256 / d>=256), LDS cross-wave
// reduce. Blocks 0..511 (XCD-affine strips, mid W), 512..513 edge rows (_s W).
// ---------------------------------------------------------------------------
__global__ __launch_bounds__(128, 2) void proj_kernel(
    const float* __restrict__ x, const u16* __restrict__ wbase,
    u16* __restrict__ qh, u16* __restrict__ ql,
    u16* __restrict__ kh, u16* __restrict__ kl,
    u16* __restrict__ vth, u16* __restrict__ vtl)
{
    __shared__ float red[6][16][64];
    const int bid = blockIdx.x;
    const bool edge = (bid >= 512);
    int sidx;
    if (!edge) { int xcd = bid & 7; sidx = (xcd >> 1) * 128 + (xcd & 1) * 64 + (bid >> 3); }
    else sidx = bid;
    const int w = threadIdx.x >> 6;
    const int lane = threadIdx.x & 63;
    const int l31 = lane & 31, hi = lane >> 5;

    const u16* wb = wbase + (edge ? (size_t)3 * 65536 : 0);
    const u16* wqh_ = wb;                 const u16* wql_ = wb + 32768;
    const u16* wkh_ = wb + 65536;         const u16* wkl_ = wb + 65536 + 32768;
    const u16* wvh_ = wb + 2 * 65536;     const u16* wvl_ = wb + 2 * 65536 + 32768;

    int growA;
    if (!edge) growA = sidx * 32 + l31;
    else {
        int e = sidx - 512, rb = l31 >> 4, i = l31 & 15;
        growA = (2 * e + rb) * 4096 + (i < 8 ? i : 4080 + i);
    }
    const float* xrow = x + (size_t)growA * 512;

    f32x16 aq[2] = {{}, {}}, ak[2] = {{}, {}}, av[2] = {{}, {}};
    const int s0 = w * 16;
    #pragma unroll 2
    for (int si = 0; si < 16; ++si) {
        const int s = s0 + si;
        const int d0 = s * 16 + 8 * hi;
        float4 xa = *(const float4*)(xrow + d0);
        float4 xb = *(const float4*)(xrow + d0 + 4);
        unsigned xh_[4], xl_[4];
        split_words(xa.x, xa.y, xh_[0], xl_[0]);
        split_words(xa.z, xa.w, xh_[1], xl_[1]);
        split_words(xb.x, xb.y, xh_[2], xl_[2]);
        split_words(xb.z, xb.w, xh_[3], xl_[3]);
        short8 xhf = mk8(xh_[0], xh_[1], xh_[2], xh_[3]);
        short8 xlf = mk8(xl_[0], xl_[1], xl_[2], xl_[3]);
        #pragma unroll
        for (int half = 0; half < 2; ++half) {
            size_t wof = (size_t)s * 1024 + (half * 32 + l31) * 16 + hi * 8;
            short8 qH = ld8(wqh_ + wof), qL = ld8(wql_ + wof);
            short8 kH = ld8(wkh_ + wof), kL = ld8(wkl_ + wof);
            short8 vH = ld8(wvh_ + wof), vL = ld8(wvl_ + wof);
            aq[half] = MFMA(xhf, qH, aq[half]);
            aq[half] = MFMA(xhf, qL, aq[half]);
            aq[half] = MFMA(xlf, qH, aq[half]);
            ak[half] = MFMA(xhf, kH, ak[half]);
            ak[half] = MFMA(xhf, kL, ak[half]);
            ak[half] = MFMA(xlf, kH, ak[half]);
            av[half] = MFMA(vH, xhf, av[half]);
            av[half] = MFMA(vL, xhf, av[half]);
            av[half] = MFMA(vH, xlf, av[half]);
        }
    }
    // cross-wave reduction: wave1 publishes q,k; wave0 publishes v
    if (w == 1) {
        #pragma unroll
        for (int h = 0; h < 2; ++h)
            #pragma unroll
            for (int r = 0; r < 16; ++r) {
                red[h][r][lane] = aq[h][r];
                red[2 + h][r][lane] = ak[h][r];
            }
    } else {
        #pragma unroll
        for (int h = 0; h < 2; ++h)
            #pragma unroll
            for (int r = 0; r < 16; ++r) red[4 + h][r][lane] = av[h][r];
    }
    __syncthreads();

    const int bv = growA >> 12, tv = growA & 4095;
    const bool vstore = edge || (tv >= 8 && tv < 4088);
    if (w == 0) {
        #pragma unroll
        for (int h = 0; h < 2; ++h)
            #pragma unroll
            for (int r = 0; r < 16; ++r) {
                aq[h][r] += red[h][r][lane];
                ak[h][r] += red[2 + h][r][lane];
            }
        #pragma unroll
        for (int half = 0; half < 2; ++half)
            #pragma unroll
            for (int r = 0; r < 16; ++r) {
                const int crow = (r & 3) + 8 * (r >> 2) + 4 * hi;
                const int col = half * 32 + l31;
                int growC; bool qkstore;
                if (!edge) {
                    int t = sidx * 32 + crow, tin = t & 4095;
                    qkstore = (tin >= 8 && tin < 4088); growC = t;
                } else {
                    int e = sidx - 512, rb = crow >> 4, i = crow & 15;
                    growC = (2 * e + rb) * 4096 + (i < 8 ? i : 4080 + i);
                    qkstore = true;
                }
                if (qkstore) {
                    size_t qo = qk_idx(growC, col);
                    split_store(aq[half][r] * 0.125f, qh + qo, ql + qo);
                    split_store(ak[half][r], kh + qo, kl + qo);
                }
            }
    } else {
        #pragma unroll
        for (int h = 0; h < 2; ++h)
            #pragma unroll
            for (int r = 0; r < 16; ++r) av[h][r] += red[4 + h][r][lane];
        if (vstore) {
            #pragma unroll
            for (int half = 0; half < 2; ++half)
                #pragma unroll
                for (int r = 0; r < 16; ++r) {
                    const int crow = (r & 3) + 8 * (r >> 2) + 4 * hi;
                    size_t vo = (size_t)(bv * 64 + (tv >> 6)) * 4096 + half * 2048
                              + ((tv & 63) >> 4) * 512 + crow * 16
                              + ((tv >> 3) & 1) * 8 + (tv & 7);
                    split_store(av[half][r], vth + vo, vtl + vo);
                }
        }
    }
}

// ---------------------------------------------------------------------------
// Flash attention: uniform chunks, XCD-affine batches, fragment-linear loads.
// __launch_bounds__(64,2): 256-VGPR budget so the batched fragment loads stay
// batched (at (64,4)/128 the live set ~160 VGPR would spill or re-serialize).
// ---------------------------------------------------------------------------
__global__ __launch_bounds__(64, 2) void flash_kernel(
    const u16* __restrict__ qhB, const u16* __restrict__ qlB,
    const u16* __restrict__ khB, const u16* __restrict__ klB,
    const u16* __restrict__ vthB, const u16* __restrict__ vtlB,
    float* __restrict__ Opart, float* __restrict__ mpart, float* __restrict__ lpart,
    int lc, int G)
{
    const int bid = blockIdx.x;
    const int xcd = bid & 7;
    const int b = xcd >> 1, par = xcd & 1;
    const int rr = bid >> 3;
    const int chunk = (G - 1) - (2 * rr + par);     // heavy chunks first (LPT)
    int qw = 0;
    for (int step = 64; step; step >>= 1) {
        int cand = qw + step;
        if (cand < 128 && chunks_before(cand, lc) <= chunk) qw = cand;
    }
    const int cloc = chunk - chunks_before(qw, lc);
    const int nt = (qw >> 1) + 1;
    const int klo = cloc << lc;
    const int khi = (nt < klo + (1 << lc)) ? nt : klo + (1 << lc);
    const int lane = threadIdx.x, l31 = lane & 31, hi = lane >> 5;

    const size_t lane_off = l31 * 16 + hi * 8;
    const size_t qbase = (size_t)(b * 128 + qw) * 2048 + lane_off;
    short8 qhf[4], qlf[4];
    #pragma unroll
    for (int s = 0; s < 4; ++s) {
        qhf[s] = ld8(qhB + qbase + s * 512);
        qlf[s] = ld8(qlB + qbase + s * 512);
    }

    f32x16 o0 = {}, o1 = {};
    float mrun = NEG_INF, lrun = 0.f;

    for (int kb = klo; kb < khi; ++kb) {
        const size_t kt = (size_t)(b * 128 + 2 * kb) * 2048 + lane_off;
        short8 k0h[4], k0l[4], k1h[4], k1l[4];
        #pragma unroll
        for (int s = 0; s < 4; ++s) {
            k0h[s] = ld8(khB + kt + s * 512);
            k0l[s] = ld8(klB + kt + s * 512);
            k1h[s] = ld8(khB + kt + 2048 + s * 512);
            k1l[s] = ld8(klB + kt + 2048 + s * 512);
        }
        f32x16 c0 = {}, c1 = {};
        __builtin_amdgcn_s_setprio(1);
        #pragma unroll
        for (int s = 0; s < 4; ++s) {
            c0 = MFMA(k0h[s], qhf[s], c0);
            c0 = MFMA(k0h[s], qlf[s], c0);
            c0 = MFMA(k0l[s], qhf[s], c0);
            c1 = MFMA(k1h[s], qhf[s], c1);
            c1 = MFMA(k1h[s], qlf[s], c1);
            c1 = MFMA(k1l[s], qhf[s], c1);
        }
        __builtin_amdgcn_s_setprio(0);
        // V sub0 loads issued before softmax (latency hidden under VALU)
        const size_t vt = (size_t)(b * 64 + kb) * 4096 + lane_off;
        short8 v0h[4], v0l[4];
        #pragma unroll
        for (int s = 0; s < 4; ++s) {
            v0h[s] = ld8(vthB + vt + s * 512);
            v0l[s] = ld8(vtlB + vt + s * 512);
        }
        if (kb == nt - 1) {
            const int qloc = l31 + 32 * (qw & 1);
            #pragma unroll
            for (int r = 0; r < 16; ++r) {
                int krow = (r & 3) + 8 * (r >> 2) + 4 * hi;
                if (krow > qloc) c0[r] = NEG_INF;
                if (krow + 32 > qloc) c1[r] = NEG_INF;
            }
        }
        float mx = NEG_INF;
        #pragma unroll
        for (int r = 0; r < 16; ++r) mx = fmaxf(mx, fmaxf(c0[r], c1[r]));
        mx = fmaxf(mx, __shfl_xor(mx, 32));
        float mnew = fmaxf(mrun, mx);
        float alpha = __expf(mrun - mnew);
        mrun = mnew;
        float sum = 0.f;
        #pragma unroll
        for (int r = 0; r < 16; ++r) { c0[r] = __expf(c0[r] - mnew); sum += c0[r]; }
        #pragma unroll
        for (int r = 0; r < 16; ++r) { c1[r] = __expf(c1[r] - mnew); sum += c1[r]; }
        sum += __shfl_xor(sum, 32);
        lrun = lrun * alpha + sum;
        #pragma unroll
        for (int r = 0; r < 16; ++r) { o0[r] *= alpha; o1[r] *= alpha; }
        short8 pbh[4], pbl[4];
        {
            unsigned wAh, wAl, wBh, wBl, wCh, wCl, wDh, wDl;
            split_words(c0[0], c0[1], wAh, wAl);  split_words(c0[2], c0[3], wBh, wBl);
            split_words(c0[4], c0[5], wCh, wCl);  split_words(c0[6], c0[7], wDh, wDl);
            permswap(wAh, wCh); permswap(wBh, wDh); permswap(wAl, wCl); permswap(wBl, wDl);
            pbh[0] = mk8(wAh, wBh, wCh, wDh); pbl[0] = mk8(wAl, wBl, wCl, wDl);
            split_words(c0[8], c0[9], wAh, wAl);  split_words(c0[10], c0[11], wBh, wBl);
            split_words(c0[12], c0[13], wCh, wCl); split_words(c0[14], c0[15], wDh, wDl);
            permswap(wAh, wCh); permswap(wBh, wDh); permswap(wAl, wCl); permswap(wBl, wDl);
            pbh[1] = mk8(wAh, wBh, wCh, wDh); pbl[1] = mk8(wAl, wBl, wCl, wDl);
            split_words(c1[0], c1[1], wAh, wAl);  split_words(c1[2], c1[3], wBh, wBl);
            split_words(c1[4], c1[5], wCh, wCl);  split_words(c1[6], c1[7], wDh, wDl);
            permswap(wAh, wCh); permswap(wBh, wDh); permswap(wAl, wCl); permswap(wBl, wDl);
            pbh[2] = mk8(wAh, wBh, wCh, wDh); pbl[2] = mk8(wAl, wBl, wCl, wDl);
            split_words(c1[8], c1[9], wAh, wAl);  split_words(c1[10], c1[11], wBh, wBl);
            split_words(c1[12], c1[13], wCh, wCl); split_words(c1[14], c1[15], wDh, wDl);
            permswap(wAh, wCh); permswap(wBh, wDh); permswap(wAl, wCl); permswap(wBl, wDl);
            pbh[3] = mk8(wAh, wBh, wCh, wDh); pbl[3] = mk8(wAl, wBl, wCl, wDl);
        }
        __builtin_amdgcn_s_setprio(1);
        #pragma unroll
        for (int s = 0; s < 4; ++s) {
            o0 = MFMA(v0h[s], pbh[s], o0);
            o0 = MFMA(v0h[s], pbl[s], o0);
            o0 = MFMA(v0l[s], pbh[s], o0);
        }
        __builtin_amdgcn_s_setprio(0);
        short8 v1h[4], v1l[4];
        #pragma unroll
        for (int s = 0; s < 4; ++s) {
            v1h[s] = ld8(vthB + vt + 2048 + s * 512);
            v1l[s] = ld8(vtlB + vt + 2048 + s * 512);
        }
        __builtin_amdgcn_s_setprio(1);
        #pragma unroll
        for (int s = 0; s < 4; ++s) {
            o1 = MFMA(v1h[s], pbh[s], o1);
            o1 = MFMA(v1h[s], pbl[s], o1);
            o1 = MFMA(v1l[s], pbh[s], o1);
        }
        __builtin_amdgcn_s_setprio(0);
    }
    const int pid = b * G + chunk;
    float* Op = Opart + (size_t)pid * 2048;   // [64 v][32 q]
    #pragma unroll
    for (int r = 0; r < 16; ++r) {
        int v0 = (r & 3) + 8 * (r >> 2) + 4 * hi;
        Op[v0 * 32 + l31] = o0[r];
        Op[(v0 + 32) * 32 + l31] = o1[r];
    }
    if (hi == 0) {
        mpart[pid * 32 + l31] = mrun;
        lpart[pid * 32 + l31] = lrun;
    }
}

// ---------------------------------------------------------------------------
// Merge: per (b,qw) combine its chunks, normalize, write out [b][t][64].
// ---------------------------------------------------------------------------
__global__ void merge_kernel(
    const float* __restrict__ Opart, const float* __restrict__ mpart,
    const float* __restrict__ lpart, float* __restrict__ out, int lc, int G)
{
    __shared__ float wgt[16][32];
    __shared__ float tr[32][65];
    const int bid = blockIdx.x;
    const int xcd = bid & 7;
    const int b = xcd >> 1;
    const int qw = (xcd & 1) * 64 + (bid >> 3);
    const int nt = (qw >> 1) + 1;
    const int CH = 1 << lc;
    const int g = (nt + CH - 1) >> lc;
    const int base = b * G + chunks_before(qw, lc);
    const int tid = threadIdx.x;
    if (tid < 32) {
        float M = NEG_INF;
        for (int s = 0; s < g; ++s) M = fmaxf(M, mpart[(base + s) * 32 + tid]);
        float L = 0.f;
        for (int s = 0; s < g; ++s)
            L += lpart[(base + s) * 32 + tid] * __expf(mpart[(base + s) * 32 + tid] - M);
        float inv = 1.0f / L;
        for (int s = 0; s < g; ++s)
            wgt[s][tid] = __expf(mpart[(base + s) * 32 + tid] - M) * inv;
    }
    __syncthreads();
    float acc[8] = {};
    for (int s = 0; s < g; ++s) {
        const float* Op = Opart + (size_t)(base + s) * 2048;
        #pragma unroll
        for (int k = 0; k < 8; ++k) {
            int i = tid + k * 256;           // i = v*32 + q
            acc[k] += wgt[s][i & 31] * Op[i];
        }
    }
    #pragma unroll
    for (int k = 0; k < 8; ++k) {
        int i = tid + k * 256;
        tr[i & 31][i >> 5] = acc[k];
    }
    __syncthreads();
    float* dst = out + ((size_t)b * 4096 + qw * 32) * 64;
    #pragma unroll
    for (int k = 0; k < 8; ++k) {
        int j = tid + k * 256;               // j = q*64 + v
        dst[j] = tr[j >> 6][j & 63];
    }
}

extern "C" void kernel_launch(void* const* d_in, const int* in_sizes, int n_in,
                              void* d_out, int out_size, void* d_ws, size_t ws_size,
                              hipStream_t stream) {
    const float* x   = (const float*)d_in[0];
    const float* Wq  = (const float*)d_in[1];
    const float* Wk  = (const float*)d_in[2];
    const float* Wv  = (const float*)d_in[3];
    const float* Wqs = (const float*)d_in[4];
    const float* Wks = (const float*)d_in[5];
    const float* Wvs = (const float*)d_in[6];
    float* out = (float*)d_out;

    char* ws = (char*)d_ws;
    const size_t MB = 1024 * 1024;
    u16* qh  = (u16*)(ws);
    u16* ql  = (u16*)(ws + 2 * MB);
    u16* kh  = (u16*)(ws + 4 * MB);
    u16* kl  = (u16*)(ws + 6 * MB);
    u16* vth = (u16*)(ws + 8 * MB);
    u16* vtl = (u16*)(ws + 10 * MB);
    u16* wbase = (u16*)(ws + 12 * MB);                 // 12 planes x 64KB
    float* mpart = (float*)(ws + 13 * MB);
    float* lpart = (float*)(ws + 13 * MB + 768 * 1024);
    float* Opart = (float*)(ws + 15 * MB);

    int LC = 2, G = 1088;                                                     // CH=4, 34MB
    if (ws_size < 15 * MB + (size_t)4 * 1088 * 8192) { LC = 3; G = 576; }     // CH=8, 18MB
    if (ws_size < 15 * MB + (size_t)4 * 576  * 8192) { LC = 4; G = 320; }     // CH=16, 10MB

    convw_kernel<<<dim3(8, 6), 256, 0, stream>>>(Wq, Wk, Wv, Wqs, Wks, Wvs, wbase);
    proj_kernel<<<514, 128, 0, stream>>>(x, wbase, qh, ql, kh, kl, vth, vtl);
    flash_kernel<<<4 * G, 64, 0, stream>>>(qh, ql, kh, kl, vth, vtl,
                                           Opart, mpart, lpart, LC, G);
    merge_kernel<<<512, 256, 0, stream>>>(Opart, mpart, lpart, out, LC, G);
}